// Round 4
// baseline (172.530 us; speedup 1.0000x reference)
//
#include <hip/hip_runtime.h>
#include <hip/hip_bf16.h>
#include <stdint.h>

#define NB 32
#define NL 512
#define ND 512

typedef __bf16 bf16x8 __attribute__((ext_vector_type(8)));
typedef float  f32x4  __attribute__((ext_vector_type(4)));

__device__ __forceinline__ unsigned short f2bf(float f) {
    uint32_t u = __float_as_uint(f);
    u = (u + 0x7fffu + ((u >> 16) & 1u)) >> 16;
    return (unsigned short)u;
}

// ============================================================================
// FAST PATH
// X' layout (per batch): [kk=l>>5][db=d>>4] subtiles of 512 bf16:
//   subtile chunk c=0..63 (16B) holds (k=(c>>4)*8+j, n=c&15): X[l=kk*32+k][d=db*16+n]
// matching the mfma_f32_16x16x32_bf16 B lane layout, so the GEMM stages with
// linear global_load_lds and reads fragments lane-linearly (conflict-free).
// The A operand (normalized gaussian weights P) is GENERATED in-register from
// per-l tables {sinv, -mean*sinv, sc} (LDS) and per-t dinv (registers).
// ============================================================================

// ---- Stage 1: fused convs -> X' bf16 (fragment layout) + ranges ----
__global__ __launch_bounds__(256) void fuse2_kernel(
    const float* __restrict__ x, const float* __restrict__ df,
    const float* __restrict__ en, const float* __restrict__ pi,
    const int* __restrict__ lens,
    const float* __restrict__ w_dur, const float* __restrict__ b_dur,
    const float* __restrict__ w_en,  const float* __restrict__ b_en,
    const float* __restrict__ w_pi,  const float* __restrict__ b_pi,
    const float* __restrict__ w_lin, const float* __restrict__ b_lin,
    unsigned short* __restrict__ Xb, float* __restrict__ ranges)
{
    const int blk = blockIdx.x;          // B * 64
    const int b   = blk >> 6;
    const int lb  = (blk & 63) << 3;     // 8 consecutive l
    const int tid = threadIdx.x;
    const int d0  = tid << 1;            // 2 consecutive d

    float we[2][3], wp[2][3], wd[2][3], bev[2], bpv[2], bdv[2], wl[2];
    #pragma unroll
    for (int q = 0; q < 2; ++q) {
        const int d = d0 + q;
        #pragma unroll
        for (int k = 0; k < 3; ++k) {
            we[q][k] = w_en[d*3+k];
            wp[q][k] = w_pi[d*3+k];
            wd[q][k] = w_dur[d*3+k];
        }
        bev[q] = b_en[d]; bpv[q] = b_pi[d]; bdv[q] = b_dur[d]; wl[q] = w_lin[d];
    }

    float acc[8];
    #pragma unroll
    for (int i = 0; i < 8; ++i) acc[i] = 0.f;

    uint4 chunk[2];
    unsigned short* cu = (unsigned short*)chunk;

    #pragma unroll
    for (int li = 0; li < 8; ++li) {
        const int l  = lb + li;
        const int bl = (b << 9) + l;
        const float dm1 = (l > 0)      ? df[bl-1] : 0.f;
        const float dc  = df[bl];
        const float dp1 = (l < NL-1)   ? df[bl+1] : 0.f;
        const float em1 = (l > 0)      ? en[bl-1] : 0.f;
        const float ec  = en[bl];
        const float ep1 = (l < NL-1)   ? en[bl+1] : 0.f;
        const float pm1 = (l > 0)      ? pi[bl-1] : 0.f;
        const float pc  = pi[bl];
        const float pp1 = (l < NL-1)   ? pi[bl+1] : 0.f;
        const float2 xv = *(const float2*)&x[(size_t)bl * ND + d0];
        #pragma unroll
        for (int q = 0; q < 2; ++q) {
            const float ev  = we[q][0]*em1 + we[q][1]*ec + we[q][2]*ep1 + bev[q];
            const float pv  = wp[q][0]*pm1 + wp[q][1]*pc + wp[q][2]*pp1 + bpv[q];
            const float xxv = (q ? xv.y : xv.x) + ev + pv;
            cu[q*8 + li] = f2bf(xxv);
            const float dv  = wd[q][0]*dm1 + wd[q][1]*dc + wd[q][2]*dp1 + bdv[q];
            acc[li] += (xxv + dv) * wl[q];
        }
    }
    #pragma unroll
    for (int q = 0; q < 2; ++q) {
        const int d = d0 + q;
        const size_t off = (size_t)b * (NL * ND)
            + (size_t)(((lb >> 5) << 5) + (d >> 4)) * 512
            + (size_t)((((lb >> 3) & 3) << 4) + (d & 15)) * 8;
        *(uint4*)&Xb[off] = chunk[q];
    }

    #pragma unroll
    for (int li = 0; li < 8; ++li)
        #pragma unroll
        for (int off = 32; off; off >>= 1)
            acc[li] += __shfl_down(acc[li], off, 64);
    __shared__ float red[4][8];
    const int lane = tid & 63, wid = tid >> 6;
    if (lane == 0)
        #pragma unroll
        for (int li = 0; li < 8; ++li) red[wid][li] = acc[li];
    __syncthreads();
    if (tid < 8) {
        const float s = red[0][tid] + red[1][tid] + red[2][tid] + red[3][tid] + b_lin[0];
        float r = fmaxf(s, 0.f) + log1pf(expf(-fabsf(s)));
        if (lb + tid >= lens[b]) r = 1.0f;
        ranges[(b << 9) + lb + tid] = r;
    }
}

// ---- Stage 2: means via inclusive scan ----
__global__ __launch_bounds__(512) void means_kernel(
    const int* __restrict__ di, float* __restrict__ means)
{
    const int b = blockIdx.x;
    const int l = threadIdx.x;
    __shared__ int s[NL];
    const int d = di[b * NL + l];
    s[l] = d;
    __syncthreads();
    #pragma unroll
    for (int off = 1; off < NL; off <<= 1) {
        const int v = (l >= off) ? s[l - off] : 0;
        __syncthreads();
        s[l] += v;
        __syncthreads();
    }
    means[b * NL + l] = 0.5f * (float)d + (float)(s[l] - d);
}

// ---- Stage 3: weights f32 output (mandatory) + dinv table ----
__global__ __launch_bounds__(256) void weights3_kernel(
    const float* __restrict__ ranges, const float* __restrict__ means,
    const int* __restrict__ lens,
    float* __restrict__ wout, float* __restrict__ dinv_out,
    int T, int Mpad)
{
    const int b = blockIdx.y;
    const int t = blockIdx.x * 256 + threadIdx.x;
    __shared__ float sm[NL], sinv[NL], sc[NL];
    const int len = lens[b];
    for (int l = threadIdx.x; l < NL; l += 256) {
        const float r = ranges[(b << 9) + l];
        const float inv = 1.f / r;
        sm[l] = means[(b << 9) + l];
        sinv[l] = inv;
        sc[l] = (l < len) ? 0.3989422804014327f * inv : 0.f;
    }
    __syncthreads();
    if (t >= Mpad) return;
    if (t >= T) { dinv_out[(size_t)b * Mpad + t] = 0.f; return; }
    const float ft = (float)t + 0.5f;
    float sum = 0.f;
    #pragma unroll 4
    for (int l = 0; l < NL; ++l) {
        const float z = (ft - sm[l]) * sinv[l];
        sum += sc[l] * __expf(-0.5f * z * z);
    }
    const float dinv = 1.f / (sum + 1e-20f);
    dinv_out[(size_t)b * Mpad + t] = dinv;
    #pragma unroll 4
    for (int l = 0; l < NL; ++l) {
        const float z = (ft - sm[l]) * sinv[l];
        wout[((size_t)(b << 9) + l) * T + t] = sc[l] * __expf(-0.5f * z * z) * dinv;
    }
}

// ---- Stage 4: bf16 MFMA GEMM, A generated in-register ----
// O[b][t][d] = sum_l P[l][t] * X[l][d]
// hw block i: xcd = i&7, slot = i>>3, g = (slot>>2)*8 + xcd, n = slot&3.
// All 4 n-works of a group (g = m*32+b) land on one XCD -> Xb panels L2-hit.
#define STAGEB(kk, buf) do {                                                    \
    const char* Bs_ = Bbase + (size_t)(kk) * 32768;                             \
    char* dst_ = ldsX + (buf) * 8192;                                           \
    _Pragma("unroll")                                                           \
    for (int c = 0; c < 2; ++c) {                                               \
        const int ch = wid * 2 + c;                                             \
        __builtin_amdgcn_global_load_lds(                                       \
            (__attribute__((address_space(1))) void*)(Bs_ + ch * 1024 + lane * 16), \
            (__attribute__((address_space(3))) void*)(dst_ + ch * 1024), 16, 0, 0); \
    }                                                                           \
} while (0)

__global__ __launch_bounds__(256) void gemm4_kernel(
    const unsigned short* __restrict__ Xb,
    const float* __restrict__ ranges, const float* __restrict__ means,
    const float* __restrict__ dinv, const int* __restrict__ lens,
    float* __restrict__ out, int T, int Mpad)
{
    __shared__ __align__(16) char ldsX[16384];     // 2 x 8KB B-tiles
    __shared__ float t_sinv[NL], t_nms[NL], t_sc[NL];
    const int tid  = threadIdx.x;
    const int lane = tid & 63, wid = tid >> 6;
    const int wm = wid >> 1, wn = wid & 1;

    const int i    = blockIdx.x;
    const int xcd  = i & 7, slot = i >> 3;
    const int g    = ((slot >> 2) << 3) + xcd;
    const int n    = slot & 3;                  // 128-d tile
    const int m    = g >> 5;                    // 128-t tile
    const int b    = g & 31;

    // build per-l tables (broadcast-friendly, once)
    const int len = lens[b];
    for (int l = tid; l < NL; l += 256) {
        const float r  = ranges[(b << 9) + l];
        const float mu = means[(b << 9) + l];
        const float sv = 1.f / r;
        t_sinv[l] = sv;
        t_nms[l]  = -mu * sv;
        t_sc[l]   = (l < len) ? 0.3989422804014327f * sv : 0.f;
    }

    const char* Bbase = (const char*)Xb + ((size_t)b * 512 + n * 8) * 1024;

    // per-t dinv into registers (4 columns per lane)
    const int tcol = m * 128 + wm * 64 + (lane & 15);
    float di[4];
    #pragma unroll
    for (int ii = 0; ii < 4; ++ii)
        di[ii] = dinv[(size_t)b * Mpad + tcol + ii * 16];
    float ft[4];
    #pragma unroll
    for (int ii = 0; ii < 4; ++ii)
        ft[ii] = (float)(tcol + ii * 16) + 0.5f;

    f32x4 acc[4][4];
    #pragma unroll
    for (int ii = 0; ii < 4; ++ii)
        #pragma unroll
        for (int jj = 0; jj < 4; ++jj) acc[ii][jj] = (f32x4){0.f, 0.f, 0.f, 0.f};

    STAGEB(0, 0);

    #pragma unroll 2
    for (int kk = 0; kk < 16; ++kk) {
        const int cur = kk & 1;
        __syncthreads();                       // buf[cur] + tables ready
        if (kk < 15) STAGEB(kk + 1, cur ^ 1);  // prefetch overlaps P-gen + MFMA

        // ---- generate A fragments in-register ----
        const int l0 = kk * 32 + ((lane >> 4) << 3);   // 8 consecutive l
        const f32x4 sv0 = *(const f32x4*)&t_sinv[l0];
        const f32x4 sv1 = *(const f32x4*)&t_sinv[l0 + 4];
        const f32x4 nm0 = *(const f32x4*)&t_nms[l0];
        const f32x4 nm1 = *(const f32x4*)&t_nms[l0 + 4];
        const f32x4 sc0 = *(const f32x4*)&t_sc[l0];
        const f32x4 sc1 = *(const f32x4*)&t_sc[l0 + 4];
        float svv[8], nmv[8], scv[8];
        #pragma unroll
        for (int jj = 0; jj < 4; ++jj) {
            svv[jj] = sv0[jj]; svv[jj+4] = sv1[jj];
            nmv[jj] = nm0[jj]; nmv[jj+4] = nm1[jj];
            scv[jj] = sc0[jj]; scv[jj+4] = sc1[jj];
        }
        bf16x8 af[4];
        #pragma unroll
        for (int jj = 0; jj < 8; ++jj) {
            #pragma unroll
            for (int ii = 0; ii < 4; ++ii) {
                const float z = fmaf(ft[ii], svv[jj], nmv[jj]);
                const float p = __expf(-0.5f * z * z) * scv[jj] * di[ii];
                af[ii][jj] = (__bf16)p;
            }
        }

        const char* bufp = ldsX + cur * 8192;
        bf16x8 bfr[4];
        #pragma unroll
        for (int jj = 0; jj < 4; ++jj)
            bfr[jj] = *(const bf16x8*)(bufp + ((wn << 2) + jj) * 1024 + lane * 16);
        #pragma unroll
        for (int ii = 0; ii < 4; ++ii)
            #pragma unroll
            for (int jj = 0; jj < 4; ++jj)
                acc[ii][jj] = __builtin_amdgcn_mfma_f32_16x16x32_bf16(af[ii], bfr[jj], acc[ii][jj], 0, 0, 0);
    }

    const int t_base = m * 128 + wm * 64;
    const int d_base = n * 128 + wn * 64 + (lane & 15);
    float* Ob = out + (size_t)b * T * ND;
    #pragma unroll
    for (int ii = 0; ii < 4; ++ii) {
        #pragma unroll
        for (int r = 0; r < 4; ++r) {
            const int t = t_base + ii * 16 + ((lane >> 4) << 2) + r;
            if (t < T) {
                #pragma unroll
                for (int jj = 0; jj < 4; ++jj)
                    Ob[(size_t)t * ND + d_base + jj * 16] = acc[ii][jj][r];
            }
        }
    }
}

// ============================================================================
// FALLBACK PATH (round-1 f32, used only if ws_size too small)
// ============================================================================
__global__ __launch_bounds__(256) void fuse_kernel(
    const float* __restrict__ x, const float* __restrict__ df,
    const float* __restrict__ en, const float* __restrict__ pi,
    const int* __restrict__ lens,
    const float* __restrict__ w_dur, const float* __restrict__ b_dur,
    const float* __restrict__ w_en,  const float* __restrict__ b_en,
    const float* __restrict__ w_pi,  const float* __restrict__ b_pi,
    const float* __restrict__ w_lin, const float* __restrict__ b_lin,
    float* __restrict__ xx, float* __restrict__ ranges)
{
    const int bl = blockIdx.x;
    const int b  = bl >> 9;
    const int l  = bl & (NL - 1);
    const int tid = threadIdx.x;
    const float dm1 = (l > 0)      ? df[bl - 1] : 0.f;
    const float d0  = df[bl];
    const float dp1 = (l < NL - 1) ? df[bl + 1] : 0.f;
    const float em1 = (l > 0)      ? en[bl - 1] : 0.f;
    const float e0  = en[bl];
    const float ep1 = (l < NL - 1) ? en[bl + 1] : 0.f;
    const float pm1 = (l > 0)      ? pi[bl - 1] : 0.f;
    const float p0  = pi[bl];
    const float pp1 = (l < NL - 1) ? pi[bl + 1] : 0.f;
    float acc = 0.f;
    #pragma unroll
    for (int d = tid; d < ND; d += 256) {
        const float xv = x[(size_t)bl * ND + d];
        const float ev = w_en[d*3]*em1 + w_en[d*3+1]*e0 + w_en[d*3+2]*ep1 + b_en[d];
        const float pv = w_pi[d*3]*pm1 + w_pi[d*3+1]*p0 + w_pi[d*3+2]*pp1 + b_pi[d];
        const float xxv = xv + ev + pv;
        xx[(size_t)bl * ND + d] = xxv;
        const float dv = w_dur[d*3]*dm1 + w_dur[d*3+1]*d0 + w_dur[d*3+2]*dp1 + b_dur[d];
        acc += (xxv + dv) * w_lin[d];
    }
    #pragma unroll
    for (int off = 32; off; off >>= 1) acc += __shfl_down(acc, off, 64);
    __shared__ float red[4];
    const int lane = tid & 63, wid = tid >> 6;
    if (lane == 0) red[wid] = acc;
    __syncthreads();
    if (tid == 0) {
        const float s = red[0] + red[1] + red[2] + red[3] + b_lin[0];
        float r = fmaxf(s, 0.f) + log1pf(expf(-fabsf(s)));
        if (l >= lens[b]) r = 1.0f;
        ranges[bl] = r;
    }
}

__global__ __launch_bounds__(256) void weights_kernel(
    const float* __restrict__ ranges, const float* __restrict__ means,
    const int* __restrict__ lens, float* __restrict__ weights, int T)
{
    const int b = blockIdx.y;
    const int t = blockIdx.x * 256 + threadIdx.x;
    __shared__ float sm[NL], sinv[NL], sc[NL];
    const int len = lens[b];
    for (int l = threadIdx.x; l < NL; l += 256) {
        const float r = ranges[b * NL + l];
        const float inv = 1.f / r;
        sm[l] = means[b * NL + l];
        sinv[l] = inv;
        sc[l] = (l < len) ? 0.3989422804014327f * inv : 0.f;
    }
    __syncthreads();
    if (t >= T) return;
    const float ft = (float)t + 0.5f;
    float sum = 0.f;
    #pragma unroll 4
    for (int l = 0; l < NL; ++l) {
        const float z = (ft - sm[l]) * sinv[l];
        sum += sc[l] * __expf(-0.5f * z * z);
    }
    const float dinv = 1.f / (sum + 1e-20f);
    #pragma unroll 4
    for (int l = 0; l < NL; ++l) {
        const float z = (ft - sm[l]) * sinv[l];
        weights[((size_t)b * NL + l) * T + t] = sc[l] * __expf(-0.5f * z * z) * dinv;
    }
}

#define BM 64
#define BN 64
#define BK 16
__global__ __launch_bounds__(256) void gemm_f32_kernel(
    const float* __restrict__ xx, const float* __restrict__ weights,
    float* __restrict__ out, int T)
{
    const int b  = blockIdx.z;
    const int t0 = blockIdx.y * BM;
    const int d0 = blockIdx.x * BN;
    const float* __restrict__ W = weights + (size_t)b * NL * T;
    const float* __restrict__ X = xx + (size_t)b * NL * ND;
    float* __restrict__ O = out + (size_t)b * T * ND;
    __shared__ float As[BK][BM];
    __shared__ float Bs[BK][BN];
    const int tid = threadIdx.x;
    const int tx = tid & 15;
    const int ty = tid >> 4;
    const int lr = tid >> 4;
    const int lc = (tid & 15) * 4;
    const bool vec_ok = (t0 + BM <= T) && ((T & 3) == 0);
    float acc[4][4] = {};
    for (int l0 = 0; l0 < NL; l0 += BK) {
        if (vec_ok) {
            *(float4*)&As[lr][lc] = *(const float4*)&W[(size_t)(l0 + lr) * T + t0 + lc];
        } else {
            #pragma unroll
            for (int j = 0; j < 4; ++j) {
                const int tcol = t0 + lc + j;
                As[lr][lc + j] = (tcol < T) ? W[(size_t)(l0 + lr) * T + tcol] : 0.f;
            }
        }
        *(float4*)&Bs[lr][lc] = *(const float4*)&X[(size_t)(l0 + lr) * ND + d0 + lc];
        __syncthreads();
        #pragma unroll
        for (int k = 0; k < BK; ++k) {
            float a[4], bb[4];
            *(float4*)a  = *(const float4*)&As[k][ty * 4];
            *(float4*)bb = *(const float4*)&Bs[k][tx * 4];
            #pragma unroll
            for (int i = 0; i < 4; ++i)
                #pragma unroll
                for (int j = 0; j < 4; ++j)
                    acc[i][j] += a[i] * bb[j];
        }
        __syncthreads();
    }
    #pragma unroll
    for (int i = 0; i < 4; ++i) {
        const int t = t0 + ty * 4 + i;
        if (t < T)
            *(float4*)&O[(size_t)t * ND + d0 + tx * 4] =
                make_float4(acc[i][0], acc[i][1], acc[i][2], acc[i][3]);
    }
}

// ============================================================================
extern "C" void kernel_launch(void* const* d_in, const int* in_sizes, int n_in,
                              void* d_out, int out_size, void* d_ws, size_t ws_size,
                              hipStream_t stream) {
    const float* x     = (const float*)d_in[0];
    const float* df    = (const float*)d_in[1];
    const int*   di    = (const int*)  d_in[2];
    const float* en    = (const float*)d_in[3];
    const float* pi    = (const float*)d_in[4];
    const int*   lens  = (const int*)  d_in[5];
    const float* w_dur = (const float*)d_in[6];
    const float* b_dur = (const float*)d_in[7];
    const float* w_en  = (const float*)d_in[8];
    const float* b_en  = (const float*)d_in[9];
    const float* w_pi  = (const float*)d_in[10];
    const float* b_pi  = (const float*)d_in[11];
    const float* w_lin = (const float*)d_in[12];
    const float* b_lin = (const float*)d_in[13];

    const int B = NB, L = NL, D = ND;
    const int T = out_size / (B * (L + D));
    const int Mpad = ((T + 127) / 128) * 128;
    const int MT = Mpad >> 7;

    float* xup  = (float*)d_out;                 // (B,T,D)
    float* wout = xup + (size_t)B * T * D;       // (B,L,T)

    const size_t XbBytes = (size_t)B * L * D * 2;
    const size_t need = XbBytes + 2 * (size_t)B * L * sizeof(float)
                      + (size_t)B * Mpad * sizeof(float);

    if (ws_size >= need) {
        unsigned short* Xb = (unsigned short*)d_ws;
        float* ranges = (float*)(Xb + (size_t)B * L * D);
        float* means  = ranges + B * L;
        float* dinv   = means + B * L;           // (B, Mpad)

        hipLaunchKernelGGL(fuse2_kernel, dim3(B * 64), dim3(256), 0, stream,
                           x, df, en, pi, lens, w_dur, b_dur, w_en, b_en,
                           w_pi, b_pi, w_lin, b_lin, Xb, ranges);
        hipLaunchKernelGGL(means_kernel, dim3(B), dim3(512), 0, stream, di, means);
        hipLaunchKernelGGL(weights3_kernel, dim3((Mpad + 255) / 256, B), dim3(256), 0, stream,
                           ranges, means, lens, wout, dinv, T, Mpad);
        hipLaunchKernelGGL(gemm4_kernel, dim3(MT * 128), dim3(256), 0, stream,
                           Xb, ranges, means, dinv, lens, xup, T, Mpad);
    } else {
        float* xx     = (float*)d_ws;
        float* ranges = xx + (size_t)B * L * D;
        float* means  = ranges + (size_t)B * L;
        hipLaunchKernelGGL(fuse_kernel, dim3(B * L), dim3(256), 0, stream,
                           x, df, en, pi, lens, w_dur, b_dur, w_en, b_en,
                           w_pi, b_pi, w_lin, b_lin, xx, ranges);
        hipLaunchKernelGGL(means_kernel, dim3(B), dim3(512), 0, stream, di, means);
        hipLaunchKernelGGL(weights_kernel, dim3((T + 255) / 256, B), dim3(256), 0, stream,
                           ranges, means, lens, wout, T);
        hipLaunchKernelGGL(gemm_f32_kernel, dim3(D / BN, (T + BM - 1) / BM, B), dim3(256), 0, stream,
                           xx, wout, xup, T);
    }
}

// Round 5
// 141.223 us; speedup vs baseline: 1.2217x; 1.2217x over previous
//
#include <hip/hip_runtime.h>
#include <hip/hip_bf16.h>
#include <stdint.h>

#define NB 32
#define NL 512
#define ND 512

typedef __bf16 bf16x8 __attribute__((ext_vector_type(8)));
typedef float  f32x4  __attribute__((ext_vector_type(4)));

__device__ __forceinline__ unsigned short f2bf(float f) {
    uint32_t u = __float_as_uint(f);
    u = (u + 0x7fffu + ((u >> 16) & 1u)) >> 16;
    return (unsigned short)u;
}

// ============================================================================
// FAST PATH
// X' layout (per batch): [kk=l>>5][db=d>>4] subtiles of 512 bf16:
//   subtile chunk c=0..63 (16B) holds (k=(c>>4)*8+j, n=c&15): X[l=kk*32+k][d=db*16+n]
// W' layout (per batch): [kk=l>>5][mb=t>>4] subtiles, same element scheme.
// Both match mfma_f32_16x16x32_bf16 A/B lane layout, so the GEMM stages with
// linear global_load_lds and reads fragments lane-linearly (conflict-free).
// ============================================================================

// ---- Stage 1: fused convs -> X' bf16 (fragment layout) + ranges ----
__global__ __launch_bounds__(256) void fuse2_kernel(
    const float* __restrict__ x, const float* __restrict__ df,
    const float* __restrict__ en, const float* __restrict__ pi,
    const int* __restrict__ lens,
    const float* __restrict__ w_dur, const float* __restrict__ b_dur,
    const float* __restrict__ w_en,  const float* __restrict__ b_en,
    const float* __restrict__ w_pi,  const float* __restrict__ b_pi,
    const float* __restrict__ w_lin, const float* __restrict__ b_lin,
    unsigned short* __restrict__ Xb, float* __restrict__ ranges)
{
    const int blk = blockIdx.x;          // B * 64
    const int b   = blk >> 6;
    const int lb  = (blk & 63) << 3;     // 8 consecutive l
    const int tid = threadIdx.x;
    const int d0  = tid << 1;            // 2 consecutive d

    float we[2][3], wp[2][3], wd[2][3], bev[2], bpv[2], bdv[2], wl[2];
    #pragma unroll
    for (int q = 0; q < 2; ++q) {
        const int d = d0 + q;
        #pragma unroll
        for (int k = 0; k < 3; ++k) {
            we[q][k] = w_en[d*3+k];
            wp[q][k] = w_pi[d*3+k];
            wd[q][k] = w_dur[d*3+k];
        }
        bev[q] = b_en[d]; bpv[q] = b_pi[d]; bdv[q] = b_dur[d]; wl[q] = w_lin[d];
    }

    float acc[8];
    #pragma unroll
    for (int i = 0; i < 8; ++i) acc[i] = 0.f;

    uint4 chunk[2];
    unsigned short* cu = (unsigned short*)chunk;

    #pragma unroll
    for (int li = 0; li < 8; ++li) {
        const int l  = lb + li;
        const int bl = (b << 9) + l;
        const float dm1 = (l > 0)      ? df[bl-1] : 0.f;
        const float dc  = df[bl];
        const float dp1 = (l < NL-1)   ? df[bl+1] : 0.f;
        const float em1 = (l > 0)      ? en[bl-1] : 0.f;
        const float ec  = en[bl];
        const float ep1 = (l < NL-1)   ? en[bl+1] : 0.f;
        const float pm1 = (l > 0)      ? pi[bl-1] : 0.f;
        const float pc  = pi[bl];
        const float pp1 = (l < NL-1)   ? pi[bl+1] : 0.f;
        const float2 xv = *(const float2*)&x[(size_t)bl * ND + d0];
        #pragma unroll
        for (int q = 0; q < 2; ++q) {
            const float ev  = we[q][0]*em1 + we[q][1]*ec + we[q][2]*ep1 + bev[q];
            const float pv  = wp[q][0]*pm1 + wp[q][1]*pc + wp[q][2]*pp1 + bpv[q];
            const float xxv = (q ? xv.y : xv.x) + ev + pv;
            cu[q*8 + li] = f2bf(xxv);
            const float dv  = wd[q][0]*dm1 + wd[q][1]*dc + wd[q][2]*dp1 + bdv[q];
            acc[li] += (xxv + dv) * wl[q];
        }
    }
    #pragma unroll
    for (int q = 0; q < 2; ++q) {
        const int d = d0 + q;
        const size_t off = (size_t)b * (NL * ND)
            + (size_t)(((lb >> 5) << 5) + (d >> 4)) * 512
            + (size_t)((((lb >> 3) & 3) << 4) + (d & 15)) * 8;
        *(uint4*)&Xb[off] = chunk[q];
    }

    #pragma unroll
    for (int li = 0; li < 8; ++li)
        #pragma unroll
        for (int off = 32; off; off >>= 1)
            acc[li] += __shfl_down(acc[li], off, 64);
    __shared__ float red[4][8];
    const int lane = tid & 63, wid = tid >> 6;
    if (lane == 0)
        #pragma unroll
        for (int li = 0; li < 8; ++li) red[wid][li] = acc[li];
    __syncthreads();
    if (tid < 8) {
        const float s = red[0][tid] + red[1][tid] + red[2][tid] + red[3][tid] + b_lin[0];
        float r = fmaxf(s, 0.f) + log1pf(expf(-fabsf(s)));
        if (lb + tid >= lens[b]) r = 1.0f;
        ranges[(b << 9) + lb + tid] = r;
    }
}

// ---- Stage 2: weights (fused duration-scan) -> wout f32 + W' bf16 ----
__global__ __launch_bounds__(256) void weights4_kernel(
    const float* __restrict__ ranges, const int* __restrict__ di,
    const int* __restrict__ lens,
    float* __restrict__ wout, unsigned short* __restrict__ Wb,
    int T, int MB)
{
    const int b = blockIdx.y;
    const int t = blockIdx.x * 256 + threadIdx.x;
    const int tid = threadIdx.x;
    const int Mpad = MB << 4;
    __shared__ float sm[NL], sinv[NL], sc[NL];
    __shared__ int sA[NL], sB[NL];

    // inclusive scan of durations (Hillis-Steele, ping-pong)
    const int l0i = tid, l1i = tid + 256;
    sA[l0i] = di[(b << 9) + l0i];
    sA[l1i] = di[(b << 9) + l1i];
    __syncthreads();
    int* src = sA; int* dst = sB;
    #pragma unroll
    for (int off = 1; off < NL; off <<= 1) {
        dst[l0i] = src[l0i] + (l0i >= off ? src[l0i - off] : 0);
        dst[l1i] = src[l1i] + (l1i >= off ? src[l1i - off] : 0);
        __syncthreads();
        int* tmp = src; src = dst; dst = tmp;
    }
    // src = inclusive cumsum; means = cum - 0.5*d
    const int len = lens[b];
    #pragma unroll
    for (int q = 0; q < 2; ++q) {
        const int l = q ? l1i : l0i;
        const int dv = di[(b << 9) + l];
        const float mu = (float)src[l] - 0.5f * (float)dv;
        const float r  = ranges[(b << 9) + l];
        const float inv = 1.f / r;
        sm[l] = mu;
        sinv[l] = inv;
        sc[l] = (l < len) ? 0.3989422804014327f * inv : 0.f;
    }
    __syncthreads();

    if (t >= Mpad) return;
    const size_t wbbase = (size_t)b * 16 * MB * 512;
    if (t >= T) {  // zero-fill pad columns so GEMM stages defined data
        const uint4 z = make_uint4(0, 0, 0, 0);
        #pragma unroll 4
        for (int lo = 0; lo < 64; ++lo) {
            const int l = lo << 3;
            const size_t off = wbbase + (size_t)((l >> 5) * MB + (t >> 4)) * 512
                             + (size_t)(((lo & 3) << 4) + (t & 15)) * 8;
            *(uint4*)&Wb[off] = z;
        }
        return;
    }
    const float ft = (float)t + 0.5f;
    float sum = 0.f;
    #pragma unroll 4
    for (int l = 0; l < NL; ++l) {
        const float z = (ft - sm[l]) * sinv[l];
        sum += sc[l] * __expf(-0.5f * z * z);
    }
    const float dinv = 1.f / (sum + 1e-20f);
    for (int l8 = 0; l8 < NL; l8 += 8) {
        uint4 pk;
        unsigned short* pu = (unsigned short*)&pk;
        #pragma unroll
        for (int j = 0; j < 8; ++j) {
            const int l = l8 + j;
            const float z = (ft - sm[l]) * sinv[l];
            const float w = sc[l] * __expf(-0.5f * z * z) * dinv;
            wout[((size_t)(b << 9) + l) * T + t] = w;
            pu[j] = f2bf(w);
        }
        const size_t off = wbbase + (size_t)((l8 >> 5) * MB + (t >> 4)) * 512
                         + (size_t)((((l8 >> 3) & 3) << 4) + (t & 15)) * 8;
        *(uint4*)&Wb[off] = pk;
    }
}

// ---- Stage 3: bf16 MFMA GEMM, 256x128 tile, 8 waves, dbuf + XCD swizzle ----
// O[b][t][d] = sum_l W[l][t] * X[l][d]
// group g = m*32 + b (one 256-t A panel), 4 n-works (128-d) each.
// hw block i: xcd = i&7, slot = i>>3, g = (slot>>2)*8 + xcd, n = slot&3.
#define STAGE256(kk, buf) do {                                                  \
    const char* As_ = Abase + (size_t)(kk) * MB * 1024;                         \
    const char* Bs_ = Bbase + (size_t)(kk) * 32768;                             \
    char* dst_ = lds + (buf) * 24576;                                           \
    _Pragma("unroll")                                                           \
    for (int c = 0; c < 2; ++c) {                                               \
        const int ch = wid * 2 + c;   /* 16 A-chunks */                         \
        __builtin_amdgcn_global_load_lds(                                       \
            (__attribute__((address_space(1))) void*)(As_ + ch * 1024 + lane * 16), \
            (__attribute__((address_space(3))) void*)(dst_ + ch * 1024), 16, 0, 0); \
    }                                                                           \
    __builtin_amdgcn_global_load_lds(                                           \
        (__attribute__((address_space(1))) void*)(Bs_ + wid * 1024 + lane * 16),    \
        (__attribute__((address_space(3))) void*)(dst_ + 16384 + wid * 1024), 16, 0, 0); \
} while (0)

__global__ __launch_bounds__(512, 4) void gemm_bf16_kernel(
    const unsigned short* __restrict__ Wb,
    const unsigned short* __restrict__ Xb,
    float* __restrict__ out, int T, int MB)
{
    __shared__ __align__(16) char lds[49152];   // 2 bufs x (A 16KB | B 8KB)
    const int tid  = threadIdx.x;
    const int lane = tid & 63, wid = tid >> 6;  // 8 waves
    const int wm = wid >> 1, wn = wid & 1;      // 4 x 2

    const int i    = blockIdx.x;
    const int xcd  = i & 7, slot = i >> 3;
    const int g    = ((slot >> 2) << 3) + xcd;  // group in [0, MT*32)
    const int n    = slot & 3;                  // 128-d tile
    const int m    = g >> 5;                    // 256-t tile
    const int b    = g & 31;

    const char* Abase = (const char*)Wb + ((size_t)b * 16 * MB + m * 16) * 1024;
    const char* Bbase = (const char*)Xb + ((size_t)b * 512 + n * 8) * 1024;

    f32x4 acc[4][4];
    #pragma unroll
    for (int ii = 0; ii < 4; ++ii)
        #pragma unroll
        for (int jj = 0; jj < 4; ++jj) acc[ii][jj] = (f32x4){0.f, 0.f, 0.f, 0.f};

    STAGE256(0, 0);

    #pragma unroll 2
    for (int kk = 0; kk < 16; ++kk) {
        const int cur = kk & 1;
        __syncthreads();                 // drains vmcnt: buf[cur] ready
        if (kk < 15) STAGE256(kk + 1, cur ^ 1);   // prefetch overlaps MFMA below
        const char* bufp = lds + cur * 24576;
        bf16x8 af[4], bfr[4];
        #pragma unroll
        for (int ii = 0; ii < 4; ++ii)
            af[ii] = *(const bf16x8*)(bufp + ((wm << 2) + ii) * 1024 + lane * 16);
        #pragma unroll
        for (int jj = 0; jj < 4; ++jj)
            bfr[jj] = *(const bf16x8*)(bufp + 16384 + ((wn << 2) + jj) * 1024 + lane * 16);
        #pragma unroll
        for (int ii = 0; ii < 4; ++ii)
            #pragma unroll
            for (int jj = 0; jj < 4; ++jj)
                acc[ii][jj] = __builtin_amdgcn_mfma_f32_16x16x32_bf16(af[ii], bfr[jj], acc[ii][jj], 0, 0, 0);
    }

    const int t_base = m * 256 + wm * 64;
    const int d_base = n * 128 + wn * 64 + (lane & 15);
    float* Ob = out + (size_t)b * T * ND;
    #pragma unroll
    for (int ii = 0; ii < 4; ++ii) {
        #pragma unroll
        for (int r = 0; r < 4; ++r) {
            const int t = t_base + ii * 16 + ((lane >> 4) << 2) + r;
            if (t < T) {
                #pragma unroll
                for (int jj = 0; jj < 4; ++jj)
                    Ob[(size_t)t * ND + d_base + jj * 16] = acc[ii][jj][r];
            }
        }
    }
}

// ============================================================================
// FALLBACK PATH (round-1 f32, used only if ws_size too small)
// ============================================================================
__global__ __launch_bounds__(512) void means_kernel(
    const int* __restrict__ di, float* __restrict__ means)
{
    const int b = blockIdx.x;
    const int l = threadIdx.x;
    __shared__ int s[NL];
    const int d = di[b * NL + l];
    s[l] = d;
    __syncthreads();
    #pragma unroll
    for (int off = 1; off < NL; off <<= 1) {
        const int v = (l >= off) ? s[l - off] : 0;
        __syncthreads();
        s[l] += v;
        __syncthreads();
    }
    means[b * NL + l] = 0.5f * (float)d + (float)(s[l] - d);
}

__global__ __launch_bounds__(256) void fuse_kernel(
    const float* __restrict__ x, const float* __restrict__ df,
    const float* __restrict__ en, const float* __restrict__ pi,
    const int* __restrict__ lens,
    const float* __restrict__ w_dur, const float* __restrict__ b_dur,
    const float* __restrict__ w_en,  const float* __restrict__ b_en,
    const float* __restrict__ w_pi,  const float* __restrict__ b_pi,
    const float* __restrict__ w_lin, const float* __restrict__ b_lin,
    float* __restrict__ xx, float* __restrict__ ranges)
{
    const int bl = blockIdx.x;
    const int b  = bl >> 9;
    const int l  = bl & (NL - 1);
    const int tid = threadIdx.x;
    const float dm1 = (l > 0)      ? df[bl - 1] : 0.f;
    const float d0  = df[bl];
    const float dp1 = (l < NL - 1) ? df[bl + 1] : 0.f;
    const float em1 = (l > 0)      ? en[bl - 1] : 0.f;
    const float e0  = en[bl];
    const float ep1 = (l < NL - 1) ? en[bl + 1] : 0.f;
    const float pm1 = (l > 0)      ? pi[bl - 1] : 0.f;
    const float p0  = pi[bl];
    const float pp1 = (l < NL - 1) ? pi[bl + 1] : 0.f;
    float acc = 0.f;
    #pragma unroll
    for (int d = tid; d < ND; d += 256) {
        const float xv = x[(size_t)bl * ND + d];
        const float ev = w_en[d*3]*em1 + w_en[d*3+1]*e0 + w_en[d*3+2]*ep1 + b_en[d];
        const float pv = w_pi[d*3]*pm1 + w_pi[d*3+1]*p0 + w_pi[d*3+2]*pp1 + b_pi[d];
        const float xxv = xv + ev + pv;
        xx[(size_t)bl * ND + d] = xxv;
        const float dv = w_dur[d*3]*dm1 + w_dur[d*3+1]*d0 + w_dur[d*3+2]*dp1 + b_dur[d];
        acc += (xxv + dv) * w_lin[d];
    }
    #pragma unroll
    for (int off = 32; off; off >>= 1) acc += __shfl_down(acc, off, 64);
    __shared__ float red[4];
    const int lane = tid & 63, wid = tid >> 6;
    if (lane == 0) red[wid] = acc;
    __syncthreads();
    if (tid == 0) {
        const float s = red[0] + red[1] + red[2] + red[3] + b_lin[0];
        float r = fmaxf(s, 0.f) + log1pf(expf(-fabsf(s)));
        if (l >= lens[b]) r = 1.0f;
        ranges[bl] = r;
    }
}

__global__ __launch_bounds__(256) void weights_kernel(
    const float* __restrict__ ranges, const float* __restrict__ means,
    const int* __restrict__ lens, float* __restrict__ weights, int T)
{
    const int b = blockIdx.y;
    const int t = blockIdx.x * 256 + threadIdx.x;
    __shared__ float sm[NL], sinv[NL], sc[NL];
    const int len = lens[b];
    for (int l = threadIdx.x; l < NL; l += 256) {
        const float r = ranges[b * NL + l];
        const float inv = 1.f / r;
        sm[l] = means[b * NL + l];
        sinv[l] = inv;
        sc[l] = (l < len) ? 0.3989422804014327f * inv : 0.f;
    }
    __syncthreads();
    if (t >= T) return;
    const float ft = (float)t + 0.5f;
    float sum = 0.f;
    #pragma unroll 4
    for (int l = 0; l < NL; ++l) {
        const float z = (ft - sm[l]) * sinv[l];
        sum += sc[l] * __expf(-0.5f * z * z);
    }
    const float dinv = 1.f / (sum + 1e-20f);
    #pragma unroll 4
    for (int l = 0; l < NL; ++l) {
        const float z = (ft - sm[l]) * sinv[l];
        weights[((size_t)b * NL + l) * T + t] = sc[l] * __expf(-0.5f * z * z) * dinv;
    }
}

#define BM 64
#define BN 64
#define BK 16
__global__ __launch_bounds__(256) void gemm_f32_kernel(
    const float* __restrict__ xx, const float* __restrict__ weights,
    float* __restrict__ out, int T)
{
    const int b  = blockIdx.z;
    const int t0 = blockIdx.y * BM;
    const int d0 = blockIdx.x * BN;
    const float* __restrict__ W = weights + (size_t)b * NL * T;
    const float* __restrict__ X = xx + (size_t)b * NL * ND;
    float* __restrict__ O = out + (size_t)b * T * ND;
    __shared__ float As[BK][BM];
    __shared__ float Bs[BK][BN];
    const int tid = threadIdx.x;
    const int tx = tid & 15;
    const int ty = tid >> 4;
    const int lr = tid >> 4;
    const int lc = (tid & 15) * 4;
    const bool vec_ok = (t0 + BM <= T) && ((T & 3) == 0);
    float acc[4][4] = {};
    for (int l0 = 0; l0 < NL; l0 += BK) {
        if (vec_ok) {
            *(float4*)&As[lr][lc] = *(const float4*)&W[(size_t)(l0 + lr) * T + t0 + lc];
        } else {
            #pragma unroll
            for (int j = 0; j < 4; ++j) {
                const int tcol = t0 + lc + j;
                As[lr][lc + j] = (tcol < T) ? W[(size_t)(l0 + lr) * T + tcol] : 0.f;
            }
        }
        *(float4*)&Bs[lr][lc] = *(const float4*)&X[(size_t)(l0 + lr) * ND + d0 + lc];
        __syncthreads();
        #pragma unroll
        for (int k = 0; k < BK; ++k) {
            float a[4], bb[4];
            *(float4*)a  = *(const float4*)&As[k][ty * 4];
            *(float4*)bb = *(const float4*)&Bs[k][tx * 4];
            #pragma unroll
            for (int i = 0; i < 4; ++i)
                #pragma unroll
                for (int j = 0; j < 4; ++j)
                    acc[i][j] += a[i] * bb[j];
        }
        __syncthreads();
    }
    #pragma unroll
    for (int i = 0; i < 4; ++i) {
        const int t = t0 + ty * 4 + i;
        if (t < T)
            *(float4*)&O[(size_t)t * ND + d0 + tx * 4] =
                make_float4(acc[i][0], acc[i][1], acc[i][2], acc[i][3]);
    }
}

// ============================================================================
extern "C" void kernel_launch(void* const* d_in, const int* in_sizes, int n_in,
                              void* d_out, int out_size, void* d_ws, size_t ws_size,
                              hipStream_t stream) {
    const float* x     = (const float*)d_in[0];
    const float* df    = (const float*)d_in[1];
    const int*   di    = (const int*)  d_in[2];
    const float* en    = (const float*)d_in[3];
    const float* pi    = (const float*)d_in[4];
    const int*   lens  = (const int*)  d_in[5];
    const float* w_dur = (const float*)d_in[6];
    const float* b_dur = (const float*)d_in[7];
    const float* w_en  = (const float*)d_in[8];
    const float* b_en  = (const float*)d_in[9];
    const float* w_pi  = (const float*)d_in[10];
    const float* b_pi  = (const float*)d_in[11];
    const float* w_lin = (const float*)d_in[12];
    const float* b_lin = (const float*)d_in[13];

    const int B = NB, L = NL, D = ND;
    const int T = out_size / (B * (L + D));
    const int Mpad = ((T + 255) / 256) * 256;   // 256-aligned for gemm tiles
    const int MB = Mpad >> 4;
    const int MT = Mpad >> 8;                   // # of 256-t tiles

    float* xup  = (float*)d_out;                 // (B,T,D)
    float* wout = xup + (size_t)B * T * D;       // (B,L,T)

    const size_t XbBytes = (size_t)B * L * D * 2;
    const size_t WbBytes = (size_t)B * Mpad * 512 * 2;
    const size_t need = XbBytes + WbBytes + (size_t)B * L * sizeof(float);

    if (ws_size >= need) {
        unsigned short* Xb = (unsigned short*)d_ws;
        unsigned short* Wb = Xb + (size_t)B * L * D;
        float* ranges = (float*)(Wb + (size_t)B * Mpad * 512);

        hipLaunchKernelGGL(fuse2_kernel, dim3(B * 64), dim3(256), 0, stream,
                           x, df, en, pi, lens, w_dur, b_dur, w_en, b_en,
                           w_pi, b_pi, w_lin, b_lin, Xb, ranges);
        hipLaunchKernelGGL(weights4_kernel, dim3(Mpad / 256, B), dim3(256), 0, stream,
                           ranges, di, lens, wout, Wb, T, MB);
        hipLaunchKernelGGL(gemm_bf16_kernel, dim3(MT * 32 * 4), dim3(512), 0, stream,
                           Wb, Xb, xup, T, MB);
    } else {
        float* xx     = (float*)d_ws;
        float* ranges = xx + (size_t)B * L * D;
        float* means  = ranges + (size_t)B * L;
        hipLaunchKernelGGL(fuse_kernel, dim3(B * L), dim3(256), 0, stream,
                           x, df, en, pi, lens, w_dur, b_dur, w_en, b_en,
                           w_pi, b_pi, w_lin, b_lin, xx, ranges);
        hipLaunchKernelGGL(means_kernel, dim3(B), dim3(512), 0, stream, di, means);
        hipLaunchKernelGGL(weights_kernel, dim3((T + 255) / 256, B), dim3(256), 0, stream,
                           ranges, means, lens, wout, T);
        hipLaunchKernelGGL(gemm_f32_kernel, dim3(D / BN, (T + BM - 1) / BM, B), dim3(256), 0, stream,
                           xx, wout, xup, T);
    }
}

// Round 6
// 122.658 us; speedup vs baseline: 1.4066x; 1.1514x over previous
//
#include <hip/hip_runtime.h>
#include <hip/hip_bf16.h>
#include <stdint.h>

#define NB 32
#define NL 512
#define ND 512

typedef __bf16 bf16x8 __attribute__((ext_vector_type(8)));
typedef float  f32x4  __attribute__((ext_vector_type(4)));

__device__ __forceinline__ unsigned short f2bf(float f) {
    uint32_t u = __float_as_uint(f);
    u = (u + 0x7fffu + ((u >> 16) & 1u)) >> 16;
    return (unsigned short)u;
}

// ============================================================================
// FAST PATH
// X' layout (per batch): [kk=l>>5][db=d>>4] subtiles of 512 bf16:
//   subtile chunk c=0..63 (16B) holds (k=(c>>4)*8+j, n=c&15): X[l=kk*32+k][d=db*16+n]
// matching the mfma_f32_16x16x32_bf16 A/B lane layout. The gaussian weights P
// are generated cooperatively into LDS in the same fragment layout (no global
// W intermediate); MFMA accumulates UNNORMALIZED p_u, dinv applied in the
// epilogue (xup = (sum_l p_u X) * dinv). wout = p_u * dinv written f32 here.
// ============================================================================

// ---- Stage 1: fused convs -> X' bf16 (fragment layout) + ranges ----
__global__ __launch_bounds__(256) void fuse2_kernel(
    const float* __restrict__ x, const float* __restrict__ df,
    const float* __restrict__ en, const float* __restrict__ pi,
    const int* __restrict__ lens,
    const float* __restrict__ w_dur, const float* __restrict__ b_dur,
    const float* __restrict__ w_en,  const float* __restrict__ b_en,
    const float* __restrict__ w_pi,  const float* __restrict__ b_pi,
    const float* __restrict__ w_lin, const float* __restrict__ b_lin,
    unsigned short* __restrict__ Xb, float* __restrict__ ranges)
{
    const int blk = blockIdx.x;          // B * 64
    const int b   = blk >> 6;
    const int lb  = (blk & 63) << 3;     // 8 consecutive l
    const int tid = threadIdx.x;
    const int d0  = tid << 1;            // 2 consecutive d

    float we[2][3], wp[2][3], wd[2][3], bev[2], bpv[2], bdv[2], wl[2];
    #pragma unroll
    for (int q = 0; q < 2; ++q) {
        const int d = d0 + q;
        #pragma unroll
        for (int k = 0; k < 3; ++k) {
            we[q][k] = w_en[d*3+k];
            wp[q][k] = w_pi[d*3+k];
            wd[q][k] = w_dur[d*3+k];
        }
        bev[q] = b_en[d]; bpv[q] = b_pi[d]; bdv[q] = b_dur[d]; wl[q] = w_lin[d];
    }

    float acc[8];
    #pragma unroll
    for (int i = 0; i < 8; ++i) acc[i] = 0.f;

    uint4 chunk[2];
    unsigned short* cu = (unsigned short*)chunk;

    #pragma unroll
    for (int li = 0; li < 8; ++li) {
        const int l  = lb + li;
        const int bl = (b << 9) + l;
        const float dm1 = (l > 0)      ? df[bl-1] : 0.f;
        const float dc  = df[bl];
        const float dp1 = (l < NL-1)   ? df[bl+1] : 0.f;
        const float em1 = (l > 0)      ? en[bl-1] : 0.f;
        const float ec  = en[bl];
        const float ep1 = (l < NL-1)   ? en[bl+1] : 0.f;
        const float pm1 = (l > 0)      ? pi[bl-1] : 0.f;
        const float pc  = pi[bl];
        const float pp1 = (l < NL-1)   ? pi[bl+1] : 0.f;
        const float2 xv = *(const float2*)&x[(size_t)bl * ND + d0];
        #pragma unroll
        for (int q = 0; q < 2; ++q) {
            const float ev  = we[q][0]*em1 + we[q][1]*ec + we[q][2]*ep1 + bev[q];
            const float pv  = wp[q][0]*pm1 + wp[q][1]*pc + wp[q][2]*pp1 + bpv[q];
            const float xxv = (q ? xv.y : xv.x) + ev + pv;
            cu[q*8 + li] = f2bf(xxv);
            const float dv  = wd[q][0]*dm1 + wd[q][1]*dc + wd[q][2]*dp1 + bdv[q];
            acc[li] += (xxv + dv) * wl[q];
        }
    }
    #pragma unroll
    for (int q = 0; q < 2; ++q) {
        const int d = d0 + q;
        const size_t off = (size_t)b * (NL * ND)
            + (size_t)(((lb >> 5) << 5) + (d >> 4)) * 512
            + (size_t)((((lb >> 3) & 3) << 4) + (d & 15)) * 8;
        *(uint4*)&Xb[off] = chunk[q];
    }

    #pragma unroll
    for (int li = 0; li < 8; ++li)
        #pragma unroll
        for (int off = 32; off; off >>= 1)
            acc[li] += __shfl_down(acc[li], off, 64);
    __shared__ float red[4][8];
    const int lane = tid & 63, wid = tid >> 6;
    if (lane == 0)
        #pragma unroll
        for (int li = 0; li < 8; ++li) red[wid][li] = acc[li];
    __syncthreads();
    if (tid < 8) {
        const float s = red[0][tid] + red[1][tid] + red[2][tid] + red[3][tid] + b_lin[0];
        float r = fmaxf(s, 0.f) + log1pf(expf(-fabsf(s)));
        if (lb + tid >= lens[b]) r = 1.0f;
        ranges[(b << 9) + lb + tid] = r;
    }
}

// ---- Stage 2: fused weights + GEMM ----
// block = (b, m: 128-t tile), 512 threads, covers all 512 d.
// hw block i: xcd=i&7, slot=i>>3, b = xcd*4 + (slot&3), m = slot>>2
// -> each XCD sees only 4 batches: their Xb panels (4 x 512KB) stay L2-resident.

#define STAGE_X(kk, buf) do {                                                   \
    const char* src_ = Bbase + (size_t)(kk) * 32768;                            \
    _Pragma("unroll")                                                           \
    for (int c = 0; c < 4; ++c) {                                               \
        const int base = (wid * 64 + c * 512) * 16;                             \
        __builtin_amdgcn_global_load_lds(                                       \
            (__attribute__((address_space(1))) void*)(src_ + base + lane * 16), \
            (__attribute__((address_space(3))) void*)(ldsX[buf] + base), 16, 0, 0); \
    }                                                                           \
} while (0)

#define GENP(kk, buf) do {                                                      \
    const int l0_ = (kk) * 32 + oct * 8;                                        \
    float pv_[8]; uint4 pk_; unsigned short* pu_ = (unsigned short*)&pk_;       \
    _Pragma("unroll")                                                           \
    for (int j = 0; j < 8; ++j) {                                               \
        const float zz = fmaf(ftv, t_sinv[l0_ + j], t_nms[l0_ + j]);            \
        pv_[j] = t_sc[l0_ + j] * __expf(-0.5f * zz * zz);                       \
        pu_[j] = f2bf(pv_[j]);                                                  \
    }                                                                           \
    if (tvalid) {                                                               \
        _Pragma("unroll")                                                       \
        for (int j = 0; j < 8; ++j)                                             \
            wout[((size_t)(b << 9) + l0_ + j) * T + tglb] = pv_[j] * myDinv;    \
    }                                                                           \
    *(uint4*)(ldsP[buf] + mbP * 1024 + (oct * 16 + (tloc & 15)) * 16) = pk_;    \
} while (0)

__global__ __launch_bounds__(512, 2) void fusedwg_kernel(
    const unsigned short* __restrict__ Xb,
    const float* __restrict__ ranges, const int* __restrict__ di,
    const int* __restrict__ lens,
    float* __restrict__ wout, float* __restrict__ xup, int T)
{
    __shared__ __align__(16) char ldsP[2][8192];    // P tiles (32l x 128t bf16)
    __shared__ __align__(16) char ldsX[2][32768];   // X tiles (32l x 512d bf16)
    __shared__ float t_sinv[NL], t_nms[NL], t_sc[NL];
    __shared__ float partial[4][128];
    __shared__ float dinvL[128];
    __shared__ int scanA[NL], scanB[NL];

    const int tid  = threadIdx.x;
    const int lane = tid & 63, wid = tid >> 6;      // 8 waves
    const int wm = wid >> 2, wn = wid & 3;          // 2m x 4n

    const int i    = blockIdx.x;
    const int xcd  = i & 7, slot = i >> 3;
    const int b    = (xcd << 2) + (slot & 3);
    const int m    = slot >> 2;                     // 128-t tile

    const int tloc = tid & 127;
    const int oct  = tid >> 7;                      // 0..3 (wave-uniform)
    const int mbP  = tloc >> 4;
    const int tglb = m * 128 + tloc;
    const bool tvalid = tglb < T;
    const float ftv = (float)tglb + 0.5f;

    // ---- duration scan -> means; tables ----
    const int dv = di[(b << 9) + tid];
    scanA[tid] = dv;
    __syncthreads();
    {
        int* src = scanA; int* dst = scanB;
        #pragma unroll
        for (int off = 1; off < NL; off <<= 1) {
            dst[tid] = src[tid] + (tid >= off ? src[tid - off] : 0);
            __syncthreads();
            int* tmp = src; src = dst; dst = tmp;
        }
        const float mu = (float)src[tid] - 0.5f * (float)dv;
        const float r  = ranges[(b << 9) + tid];
        const float inv = 1.f / r;
        t_sinv[tid] = inv;
        t_nms[tid]  = -mu * inv;
        t_sc[tid]   = (tid < lens[b]) ? 0.3989422804014327f * inv : 0.f;
    }
    __syncthreads();

    // ---- denominator pre-pass: 4 groups of 128 l per t ----
    {
        float s = 0.f;
        const int lbeg = oct * 128;
        #pragma unroll 4
        for (int l = lbeg; l < lbeg + 128; ++l) {
            const float zz = fmaf(ftv, t_sinv[l], t_nms[l]);
            s += t_sc[l] * __expf(-0.5f * zz * zz);
        }
        partial[oct][tloc] = s;
    }
    __syncthreads();
    if (tid < 128) {
        const float sum = partial[0][tid] + partial[1][tid] + partial[2][tid] + partial[3][tid];
        dinvL[tid] = (m * 128 + tid < T) ? 1.f / (sum + 1e-20f) : 0.f;
    }
    __syncthreads();
    const float myDinv = dinvL[tloc];

    const char* Bbase = (const char*)Xb + (size_t)b * (NL * ND * 2);

    f32x4 acc[4][8];
    #pragma unroll
    for (int ii = 0; ii < 4; ++ii)
        #pragma unroll
        for (int jj = 0; jj < 8; ++jj) acc[ii][jj] = (f32x4){0.f, 0.f, 0.f, 0.f};

    STAGE_X(0, 0);
    GENP(0, 0);

    for (int k = 0; k < 16; ++k) {
        const int cur = k & 1;
        __syncthreads();                          // X_k drained; P_k visible
        if (k < 15) {
            STAGE_X(k + 1, cur ^ 1);              // in flight across MFMA_k
            GENP(k + 1, cur ^ 1);                 // VALU overlaps loads
        }
        bf16x8 af[4], bfr[8];
        #pragma unroll
        for (int ii = 0; ii < 4; ++ii)
            af[ii] = *(const bf16x8*)(ldsP[cur] + ((wm << 2) + ii) * 1024 + lane * 16);
        #pragma unroll
        for (int jj = 0; jj < 8; ++jj)
            bfr[jj] = *(const bf16x8*)(ldsX[cur] + ((wn << 3) + jj) * 1024 + lane * 16);
        #pragma unroll
        for (int ii = 0; ii < 4; ++ii)
            #pragma unroll
            for (int jj = 0; jj < 8; ++jj)
                acc[ii][jj] = __builtin_amdgcn_mfma_f32_16x16x32_bf16(af[ii], bfr[jj], acc[ii][jj], 0, 0, 0);
    }

    // ---- epilogue: apply dinv, store xup ----
    const int d_base = (wn << 7) + (lane & 15);
    float* Ob = xup + (size_t)b * T * ND;
    #pragma unroll
    for (int ii = 0; ii < 4; ++ii) {
        #pragma unroll
        for (int r = 0; r < 4; ++r) {
            const int tl2 = (wm << 6) + ii * 16 + ((lane >> 4) << 2) + r;
            const int t = m * 128 + tl2;
            if (t < T) {
                const float dsc = dinvL[tl2];
                #pragma unroll
                for (int jj = 0; jj < 8; ++jj)
                    Ob[(size_t)t * ND + d_base + jj * 16] = acc[ii][jj][r] * dsc;
            }
        }
    }
}

// ============================================================================
// FALLBACK PATH (round-1 f32, used only if ws_size too small)
// ============================================================================
__global__ __launch_bounds__(512) void means_kernel(
    const int* __restrict__ di, float* __restrict__ means)
{
    const int b = blockIdx.x;
    const int l = threadIdx.x;
    __shared__ int s[NL];
    const int d = di[b * NL + l];
    s[l] = d;
    __syncthreads();
    #pragma unroll
    for (int off = 1; off < NL; off <<= 1) {
        const int v = (l >= off) ? s[l - off] : 0;
        __syncthreads();
        s[l] += v;
        __syncthreads();
    }
    means[b * NL + l] = 0.5f * (float)d + (float)(s[l] - d);
}

__global__ __launch_bounds__(256) void fuse_kernel(
    const float* __restrict__ x, const float* __restrict__ df,
    const float* __restrict__ en, const float* __restrict__ pi,
    const int* __restrict__ lens,
    const float* __restrict__ w_dur, const float* __restrict__ b_dur,
    const float* __restrict__ w_en,  const float* __restrict__ b_en,
    const float* __restrict__ w_pi,  const float* __restrict__ b_pi,
    const float* __restrict__ w_lin, const float* __restrict__ b_lin,
    float* __restrict__ xx, float* __restrict__ ranges)
{
    const int bl = blockIdx.x;
    const int b  = bl >> 9;
    const int l  = bl & (NL - 1);
    const int tid = threadIdx.x;
    const float dm1 = (l > 0)      ? df[bl - 1] : 0.f;
    const float d0  = df[bl];
    const float dp1 = (l < NL - 1) ? df[bl + 1] : 0.f;
    const float em1 = (l > 0)      ? en[bl - 1] : 0.f;
    const float e0  = en[bl];
    const float ep1 = (l < NL - 1) ? en[bl + 1] : 0.f;
    const float pm1 = (l > 0)      ? pi[bl - 1] : 0.f;
    const float p0  = pi[bl];
    const float pp1 = (l < NL - 1) ? pi[bl + 1] : 0.f;
    float acc = 0.f;
    #pragma unroll
    for (int d = tid; d < ND; d += 256) {
        const float xv = x[(size_t)bl * ND + d];
        const float ev = w_en[d*3]*em1 + w_en[d*3+1]*e0 + w_en[d*3+2]*ep1 + b_en[d];
        const float pv = w_pi[d*3]*pm1 + w_pi[d*3+1]*p0 + w_pi[d*3+2]*pp1 + b_pi[d];
        const float xxv = xv + ev + pv;
        xx[(size_t)bl * ND + d] = xxv;
        const float dv = w_dur[d*3]*dm1 + w_dur[d*3+1]*d0 + w_dur[d*3+2]*dp1 + b_dur[d];
        acc += (xxv + dv) * w_lin[d];
    }
    #pragma unroll
    for (int off = 32; off; off >>= 1) acc += __shfl_down(acc, off, 64);
    __shared__ float red[4];
    const int lane = tid & 63, wid = tid >> 6;
    if (lane == 0) red[wid] = acc;
    __syncthreads();
    if (tid == 0) {
        const float s = red[0] + red[1] + red[2] + red[3] + b_lin[0];
        float r = fmaxf(s, 0.f) + log1pf(expf(-fabsf(s)));
        if (l >= lens[b]) r = 1.0f;
        ranges[bl] = r;
    }
}

__global__ __launch_bounds__(256) void weights_kernel(
    const float* __restrict__ ranges, const float* __restrict__ means,
    const int* __restrict__ lens, float* __restrict__ weights, int T)
{
    const int b = blockIdx.y;
    const int t = blockIdx.x * 256 + threadIdx.x;
    __shared__ float sm[NL], sinv[NL], sc[NL];
    const int len = lens[b];
    for (int l = threadIdx.x; l < NL; l += 256) {
        const float r = ranges[b * NL + l];
        const float inv = 1.f / r;
        sm[l] = means[b * NL + l];
        sinv[l] = inv;
        sc[l] = (l < len) ? 0.3989422804014327f * inv : 0.f;
    }
    __syncthreads();
    if (t >= T) return;
    const float ft = (float)t + 0.5f;
    float sum = 0.f;
    #pragma unroll 4
    for (int l = 0; l < NL; ++l) {
        const float z = (ft - sm[l]) * sinv[l];
        sum += sc[l] * __expf(-0.5f * z * z);
    }
    const float dinv = 1.f / (sum + 1e-20f);
    #pragma unroll 4
    for (int l = 0; l < NL; ++l) {
        const float z = (ft - sm[l]) * sinv[l];
        weights[((size_t)b * NL + l) * T + t] = sc[l] * __expf(-0.5f * z * z) * dinv;
    }
}

#define BM 64
#define BN 64
#define BK 16
__global__ __launch_bounds__(256) void gemm_f32_kernel(
    const float* __restrict__ xx, const float* __restrict__ weights,
    float* __restrict__ out, int T)
{
    const int b  = blockIdx.z;
    const int t0 = blockIdx.y * BM;
    const int d0 = blockIdx.x * BN;
    const float* __restrict__ W = weights + (size_t)b * NL * T;
    const float* __restrict__ X = xx + (size_t)b * NL * ND;
    float* __restrict__ O = out + (size_t)b * T * ND;
    __shared__ float As[BK][BM];
    __shared__ float Bs[BK][BN];
    const int tid = threadIdx.x;
    const int tx = tid & 15;
    const int ty = tid >> 4;
    const int lr = tid >> 4;
    const int lc = (tid & 15) * 4;
    const bool vec_ok = (t0 + BM <= T) && ((T & 3) == 0);
    float acc[4][4] = {};
    for (int l0 = 0; l0 < NL; l0 += BK) {
        if (vec_ok) {
            *(float4*)&As[lr][lc] = *(const float4*)&W[(size_t)(l0 + lr) * T + t0 + lc];
        } else {
            #pragma unroll
            for (int j = 0; j < 4; ++j) {
                const int tcol = t0 + lc + j;
                As[lr][lc + j] = (tcol < T) ? W[(size_t)(l0 + lr) * T + tcol] : 0.f;
            }
        }
        *(float4*)&Bs[lr][lc] = *(const float4*)&X[(size_t)(l0 + lr) * ND + d0 + lc];
        __syncthreads();
        #pragma unroll
        for (int k = 0; k < BK; ++k) {
            float a[4], bb[4];
            *(float4*)a  = *(const float4*)&As[k][ty * 4];
            *(float4*)bb = *(const float4*)&Bs[k][tx * 4];
            #pragma unroll
            for (int i = 0; i < 4; ++i)
                #pragma unroll
                for (int j = 0; j < 4; ++j)
                    acc[i][j] += a[i] * bb[j];
        }
        __syncthreads();
    }
    #pragma unroll
    for (int i = 0; i < 4; ++i) {
        const int t = t0 + ty * 4 + i;
        if (t < T)
            *(float4*)&O[(size_t)t * ND + d0 + tx * 4] =
                make_float4(acc[i][0], acc[i][1], acc[i][2], acc[i][3]);
    }
}

// ============================================================================
extern "C" void kernel_launch(void* const* d_in, const int* in_sizes, int n_in,
                              void* d_out, int out_size, void* d_ws, size_t ws_size,
                              hipStream_t stream) {
    const float* x     = (const float*)d_in[0];
    const float* df    = (const float*)d_in[1];
    const int*   di    = (const int*)  d_in[2];
    const float* en    = (const float*)d_in[3];
    const float* pi    = (const float*)d_in[4];
    const int*   lens  = (const int*)  d_in[5];
    const float* w_dur = (const float*)d_in[6];
    const float* b_dur = (const float*)d_in[7];
    const float* w_en  = (const float*)d_in[8];
    const float* b_en  = (const float*)d_in[9];
    const float* w_pi  = (const float*)d_in[10];
    const float* b_pi  = (const float*)d_in[11];
    const float* w_lin = (const float*)d_in[12];
    const float* b_lin = (const float*)d_in[13];

    const int B = NB, L = NL, D = ND;
    const int T = out_size / (B * (L + D));
    const int MT = (T + 127) / 128;              // # of 128-t tiles

    float* xup  = (float*)d_out;                 // (B,T,D)
    float* wout = xup + (size_t)B * T * D;       // (B,L,T)

    const size_t XbBytes = (size_t)B * L * D * 2;
    const size_t need = XbBytes + (size_t)B * L * sizeof(float);

    if (ws_size >= need) {
        unsigned short* Xb = (unsigned short*)d_ws;
        float* ranges = (float*)(Xb + (size_t)B * L * D);

        hipLaunchKernelGGL(fuse2_kernel, dim3(B * 64), dim3(256), 0, stream,
                           x, df, en, pi, lens, w_dur, b_dur, w_en, b_en,
                           w_pi, b_pi, w_lin, b_lin, Xb, ranges);
        hipLaunchKernelGGL(fusedwg_kernel, dim3(MT * 32), dim3(512), 0, stream,
                           Xb, ranges, di, lens, wout, xup, T);
    } else {
        float* xx     = (float*)d_ws;
        float* ranges = xx + (size_t)B * L * D;
        float* means  = ranges + (size_t)B * L;
        hipLaunchKernelGGL(fuse_kernel, dim3(B * L), dim3(256), 0, stream,
                           x, df, en, pi, lens, w_dur, b_dur, w_en, b_en,
                           w_pi, b_pi, w_lin, b_lin, xx, ranges);
        hipLaunchKernelGGL(means_kernel, dim3(B), dim3(512), 0, stream, di, means);
        hipLaunchKernelGGL(weights_kernel, dim3((T + 255) / 256, B), dim3(256), 0, stream,
                           ranges, means, lens, wout, T);
        hipLaunchKernelGGL(gemm_f32_kernel, dim3(D / BN, (T + BM - 1) / BM, B), dim3(256), 0, stream,
                           xx, wout, xup, T);
    }
}

// Round 7
// 101.480 us; speedup vs baseline: 1.7001x; 1.2087x over previous
//
#include <hip/hip_runtime.h>
#include <hip/hip_bf16.h>
#include <stdint.h>

#define NB 32
#define NL 512
#define ND 512

typedef __bf16 bf16x8 __attribute__((ext_vector_type(8)));
typedef float  f32x4  __attribute__((ext_vector_type(4)));

__device__ __forceinline__ unsigned short f2bf(float f) {
    uint32_t u = __float_as_uint(f);
    u = (u + 0x7fffu + ((u >> 16) & 1u)) >> 16;
    return (unsigned short)u;
}

// ============================================================================
// FAST PATH
// X' layout (per batch): [kk=l>>5][db=d>>4] subtiles of 512 bf16:
//   subtile chunk c=0..63 (16B) holds (k=(c>>4)*8+j, n=c&15): X[l=kk*32+k][d=db*16+n]
// matching the mfma_f32_16x16x32_bf16 A/B lane layout. Gaussian weights P are
// generated cooperatively into LDS (no global W intermediate); MFMA uses
// UNNORMALIZED p_u; dinv applied in epilogue. wout = p_u * dinv written here.
// fusedwg2: 64-t tiles, 8 waves (1m x 8n), acc[4][4] (64 VGPR), 80.1KB LDS
// -> 2 blocks/CU; counted-vmcnt barrier; LDS-bounced coalesced xup epilogue.
// ============================================================================

// ---- Stage 1: fused convs -> X' bf16 (fragment layout) + ranges ----
__global__ __launch_bounds__(256) void fuse2_kernel(
    const float* __restrict__ x, const float* __restrict__ df,
    const float* __restrict__ en, const float* __restrict__ pi,
    const int* __restrict__ lens,
    const float* __restrict__ w_dur, const float* __restrict__ b_dur,
    const float* __restrict__ w_en,  const float* __restrict__ b_en,
    const float* __restrict__ w_pi,  const float* __restrict__ b_pi,
    const float* __restrict__ w_lin, const float* __restrict__ b_lin,
    unsigned short* __restrict__ Xb, float* __restrict__ ranges)
{
    const int blk = blockIdx.x;          // B * 64
    const int b   = blk >> 6;
    const int lb  = (blk & 63) << 3;     // 8 consecutive l
    const int tid = threadIdx.x;
    const int d0  = tid << 1;            // 2 consecutive d

    float we[2][3], wp[2][3], wd[2][3], bev[2], bpv[2], bdv[2], wl[2];
    #pragma unroll
    for (int q = 0; q < 2; ++q) {
        const int d = d0 + q;
        #pragma unroll
        for (int k = 0; k < 3; ++k) {
            we[q][k] = w_en[d*3+k];
            wp[q][k] = w_pi[d*3+k];
            wd[q][k] = w_dur[d*3+k];
        }
        bev[q] = b_en[d]; bpv[q] = b_pi[d]; bdv[q] = b_dur[d]; wl[q] = w_lin[d];
    }

    float acc[8];
    #pragma unroll
    for (int i = 0; i < 8; ++i) acc[i] = 0.f;

    uint4 chunk[2];
    unsigned short* cu = (unsigned short*)chunk;

    #pragma unroll
    for (int li = 0; li < 8; ++li) {
        const int l  = lb + li;
        const int bl = (b << 9) + l;
        const float dm1 = (l > 0)      ? df[bl-1] : 0.f;
        const float dc  = df[bl];
        const float dp1 = (l < NL-1)   ? df[bl+1] : 0.f;
        const float em1 = (l > 0)      ? en[bl-1] : 0.f;
        const float ec  = en[bl];
        const float ep1 = (l < NL-1)   ? en[bl+1] : 0.f;
        const float pm1 = (l > 0)      ? pi[bl-1] : 0.f;
        const float pc  = pi[bl];
        const float pp1 = (l < NL-1)   ? pi[bl+1] : 0.f;
        const float2 xv = *(const float2*)&x[(size_t)bl * ND + d0];
        #pragma unroll
        for (int q = 0; q < 2; ++q) {
            const float ev  = we[q][0]*em1 + we[q][1]*ec + we[q][2]*ep1 + bev[q];
            const float pv  = wp[q][0]*pm1 + wp[q][1]*pc + wp[q][2]*pp1 + bpv[q];
            const float xxv = (q ? xv.y : xv.x) + ev + pv;
            cu[q*8 + li] = f2bf(xxv);
            const float dv  = wd[q][0]*dm1 + wd[q][1]*dc + wd[q][2]*dp1 + bdv[q];
            acc[li] += (xxv + dv) * wl[q];
        }
    }
    #pragma unroll
    for (int q = 0; q < 2; ++q) {
        const int d = d0 + q;
        const size_t off = (size_t)b * (NL * ND)
            + (size_t)(((lb >> 5) << 5) + (d >> 4)) * 512
            + (size_t)((((lb >> 3) & 3) << 4) + (d & 15)) * 8;
        *(uint4*)&Xb[off] = chunk[q];
    }

    #pragma unroll
    for (int li = 0; li < 8; ++li)
        #pragma unroll
        for (int off = 32; off; off >>= 1)
            acc[li] += __shfl_down(acc[li], off, 64);
    __shared__ float red[4][8];
    const int lane = tid & 63, wid = tid >> 6;
    if (lane == 0)
        #pragma unroll
        for (int li = 0; li < 8; ++li) red[wid][li] = acc[li];
    __syncthreads();
    if (tid < 8) {
        const float s = red[0][tid] + red[1][tid] + red[2][tid] + red[3][tid] + b_lin[0];
        float r = fmaxf(s, 0.f) + log1pf(expf(-fabsf(s)));
        if (lb + tid >= lens[b]) r = 1.0f;
        ranges[(b << 9) + lb + tid] = r;
    }
}

// ---- Stage 2: fused weights + GEMM, 64-t tiles ----
// hw block i: xcd=i&7, slot=i>>3, b = xcd*4 + (slot&3), m = slot>>2.
// LDS map (80128 B total):
//   [0, 65536)      ldsX[2][32768]   (prologue: scanA@0, scanB@2048, partial@4096)
//   [65536, 73728)  ldsP[2][4096]
//   [73728, 75776)  t_sinv[512]
//   [75776, 77824)  t_nms[512]
//   [77824, 79872)  t_sc[512]
//   [79872, 80128)  dinvL[64]

#define STAGE_X2(kk, buf) do {                                                  \
    const char* src_ = Bbase + (size_t)(kk) * 32768;                            \
    char* dst_ = smem + (buf) * 32768;                                          \
    _Pragma("unroll")                                                           \
    for (int c = 0; c < 4; ++c) {                                               \
        const int o_ = (wid * 4 + c) * 1024;                                    \
        __builtin_amdgcn_global_load_lds(                                       \
            (__attribute__((address_space(1))) void*)(src_ + o_ + lane * 16),   \
            (__attribute__((address_space(3))) void*)(dst_ + o_), 16, 0, 0);    \
    }                                                                           \
} while (0)

#define GENP2(kk, buf) do {                                                     \
    const int l0_ = (kk) * 32 + oct * 4;                                        \
    float pv_[4];                                                               \
    unsigned short pu_[4];                                                      \
    _Pragma("unroll")                                                           \
    for (int j = 0; j < 4; ++j) {                                               \
        const float zz = fmaf(ftv, t_sinv[l0_ + j], t_nms[l0_ + j]);            \
        pv_[j] = t_sc[l0_ + j] * __expf(-0.5f * zz * zz);                       \
        pu_[j] = f2bf(pv_[j]);                                                  \
    }                                                                           \
    char* pd_ = smem + 65536 + (buf) * 4096 + (tloc >> 4) * 1024               \
              + (((oct >> 1) << 4) + (tloc & 15)) * 16 + ((oct & 1) << 3);      \
    *(uint2*)pd_ = *(uint2*)pu_;                                                \
    if (tvalid) {                                                               \
        _Pragma("unroll")                                                       \
        for (int j = 0; j < 4; ++j)                                             \
            wout[((size_t)(b << 9) + l0_ + j) * T + tglb] = pv_[j] * myDinv;    \
    }                                                                           \
} while (0)

__global__ __launch_bounds__(512, 4) void fusedwg2_kernel(
    const unsigned short* __restrict__ Xb,
    const float* __restrict__ ranges, const int* __restrict__ di,
    const int* __restrict__ lens,
    float* __restrict__ wout, float* __restrict__ xup, int T)
{
    __shared__ __align__(16) char smem[80128];
    float* t_sinv = (float*)(smem + 73728);
    float* t_nms  = (float*)(smem + 75776);
    float* t_sc   = (float*)(smem + 77824);
    float* dinvL  = (float*)(smem + 79872);
    int*   scanA  = (int*)smem;            // prologue-only aliases (die before
    int*   scanB  = (int*)(smem + 2048);   //  STAGE_X2(0,0) overwrites)
    float* partial = (float*)(smem + 4096);

    const int tid  = threadIdx.x;
    const int lane = tid & 63, wid = tid >> 6;      // 8 waves
    const int wn   = wid;                           // 1m x 8n

    const int i    = blockIdx.x;
    const int xcd  = i & 7, slot = i >> 3;
    const int b    = (xcd << 2) + (slot & 3);
    const int m    = slot >> 2;                     // 64-t tile
    const int m64  = m << 6;

    const int tloc = tid & 63;
    const int oct  = tid >> 6;                      // 0..7 == wid
    const int tglb = m64 + tloc;
    const bool tvalid = tglb < T;
    const float ftv = (float)tglb + 0.5f;

    // ---- prologue: duration scan -> tables ----
    const int dv = di[(b << 9) + tid];
    scanA[tid] = dv;
    __syncthreads();
    {
        int* src = scanA; int* dst = scanB;
        #pragma unroll
        for (int off = 1; off < NL; off <<= 1) {
            dst[tid] = src[tid] + (tid >= off ? src[tid - off] : 0);
            __syncthreads();
            int* tmp = src; src = dst; dst = tmp;
        }
        const float mu = (float)src[tid] - 0.5f * (float)dv;
        const float r  = ranges[(b << 9) + tid];
        const float inv = 1.f / r;
        t_sinv[tid] = inv;
        t_nms[tid]  = -mu * inv;
        t_sc[tid]   = (tid < lens[b]) ? 0.3989422804014327f * inv : 0.f;
    }
    __syncthreads();

    // ---- denominator pre-pass: 8 octs x 64 l ----
    {
        float s = 0.f;
        const int lbeg = oct << 6;
        #pragma unroll 4
        for (int l = lbeg; l < lbeg + 64; ++l) {
            const float zz = fmaf(ftv, t_sinv[l], t_nms[l]);
            s += t_sc[l] * __expf(-0.5f * zz * zz);
        }
        partial[(oct << 6) + tloc] = s;
    }
    __syncthreads();
    if (tid < 64) {
        float sum = 0.f;
        #pragma unroll
        for (int o = 0; o < 8; ++o) sum += partial[(o << 6) + tid];
        dinvL[tid] = 1.f / (sum + 1e-20f);
    }
    __syncthreads();                      // dinvL ready; scan region now free
    const float myDinv = dinvL[tloc];

    const char* Bbase = (const char*)Xb + (size_t)b * (NL * ND * 2);

    f32x4 acc[4][4];
    #pragma unroll
    for (int ii = 0; ii < 4; ++ii)
        #pragma unroll
        for (int jj = 0; jj < 4; ++jj) acc[ii][jj] = (f32x4){0.f, 0.f, 0.f, 0.f};

    STAGE_X2(0, 0);
    __builtin_amdgcn_sched_barrier(0);
    GENP2(0, 0);

    for (int k = 0; k < 16; ++k) {
        // counted barrier: the 4 youngest VM ops are this wave's wout stores;
        // all gload_lds for buf[cur] are older -> complete. lgkmcnt(0) makes
        // the ldsP write visible; raw s_barrier avoids the vmcnt(0) drain.
        asm volatile("s_waitcnt vmcnt(4) lgkmcnt(0)" ::: "memory");
        __builtin_amdgcn_s_barrier();
        __builtin_amdgcn_sched_barrier(0);
        const int cur = k & 1;
        if (k < 15) {
            STAGE_X2(k + 1, cur ^ 1);
            __builtin_amdgcn_sched_barrier(0);   // keep stores younger than loads
            GENP2(k + 1, cur ^ 1);
        }
        bf16x8 af[4], bfr[4];
        #pragma unroll
        for (int ii = 0; ii < 4; ++ii)
            af[ii] = *(const bf16x8*)(smem + 65536 + cur * 4096 + ii * 1024 + lane * 16);
        #pragma unroll
        for (int jj = 0; jj < 4; ++jj)
            bfr[jj] = *(const bf16x8*)(smem + cur * 32768 + ((wn << 2) + jj) * 1024 + lane * 16);
        #pragma unroll
        for (int ii = 0; ii < 4; ++ii)
            #pragma unroll
            for (int jj = 0; jj < 4; ++jj)
                acc[ii][jj] = __builtin_amdgcn_mfma_f32_16x16x32_bf16(af[ii], bfr[jj], acc[ii][jj], 0, 0, 0);
    }

    // ---- epilogue: LDS-bounce -> 1KB coalesced xup stores ----
    // chunk c: t-rows [c*16, c*16+16), LDS rows stride 516 dwords (2-way ok)
    float* lf = (float*)smem;
    float* Ob = xup + (size_t)b * T * ND;
    #pragma unroll
    for (int c = 0; c < 4; ++c) {
        __syncthreads();
        #pragma unroll
        for (int jj = 0; jj < 4; ++jj)
            #pragma unroll
            for (int r = 0; r < 4; ++r) {
                const int row = ((lane >> 4) << 2) + r;           // 0..15
                const int col = (wn << 6) + (jj << 4) + (lane & 15);
                lf[row * 516 + col] = acc[c][jj][r];
            }
        __syncthreads();
        const int trow = tid >> 7;            // 0..3 (wave-uniform)
        const int colq = (tid & 127) << 2;
        #pragma unroll
        for (int s = 0; s < 4; ++s) {
            const int row = trow + (s << 2);
            const int t = m64 + (c << 4) + row;
            if (t < T) {
                const float dsc = dinvL[(c << 4) + row];
                f32x4 v = *(const f32x4*)(lf + row * 516 + colq);
                v[0] *= dsc; v[1] *= dsc; v[2] *= dsc; v[3] *= dsc;
                *(f32x4*)&Ob[(size_t)t * ND + colq] = v;
            }
        }
    }
}

// ============================================================================
// FALLBACK PATH (round-1 f32, used only if ws_size too small)
// ============================================================================
__global__ __launch_bounds__(512) void means_kernel(
    const int* __restrict__ di, float* __restrict__ means)
{
    const int b = blockIdx.x;
    const int l = threadIdx.x;
    __shared__ int s[NL];
    const int d = di[b * NL + l];
    s[l] = d;
    __syncthreads();
    #pragma unroll
    for (int off = 1; off < NL; off <<= 1) {
        const int v = (l >= off) ? s[l - off] : 0;
        __syncthreads();
        s[l] += v;
        __syncthreads();
    }
    means[b * NL + l] = 0.5f * (float)d + (float)(s[l] - d);
}

__global__ __launch_bounds__(256) void fuse_kernel(
    const float* __restrict__ x, const float* __restrict__ df,
    const float* __restrict__ en, const float* __restrict__ pi,
    const int* __restrict__ lens,
    const float* __restrict__ w_dur, const float* __restrict__ b_dur,
    const float* __restrict__ w_en,  const float* __restrict__ b_en,
    const float* __restrict__ w_pi,  const float* __restrict__ b_pi,
    const float* __restrict__ w_lin, const float* __restrict__ b_lin,
    float* __restrict__ xx, float* __restrict__ ranges)
{
    const int bl = blockIdx.x;
    const int b  = bl >> 9;
    const int l  = bl & (NL - 1);
    const int tid = threadIdx.x;
    const float dm1 = (l > 0)      ? df[bl - 1] : 0.f;
    const float d0  = df[bl];
    const float dp1 = (l < NL - 1) ? df[bl + 1] : 0.f;
    const float em1 = (l > 0)      ? en[bl - 1] : 0.f;
    const float e0  = en[bl];
    const float ep1 = (l < NL - 1) ? en[bl + 1] : 0.f;
    const float pm1 = (l > 0)      ? pi[bl - 1] : 0.f;
    const float p0  = pi[bl];
    const float pp1 = (l < NL - 1) ? pi[bl + 1] : 0.f;
    float acc = 0.f;
    #pragma unroll
    for (int d = tid; d < ND; d += 256) {
        const float xv = x[(size_t)bl * ND + d];
        const float ev = w_en[d*3]*em1 + w_en[d*3+1]*e0 + w_en[d*3+2]*ep1 + b_en[d];
        const float pv = w_pi[d*3]*pm1 + w_pi[d*3+1]*p0 + w_pi[d*3+2]*pp1 + b_pi[d];
        const float xxv = xv + ev + pv;
        xx[(size_t)bl * ND + d] = xxv;
        const float dv = w_dur[d*3]*dm1 + w_dur[d*3+1]*d0 + w_dur[d*3+2]*dp1 + b_dur[d];
        acc += (xxv + dv) * w_lin[d];
    }
    #pragma unroll
    for (int off = 32; off; off >>= 1) acc += __shfl_down(acc, off, 64);
    __shared__ float red[4];
    const int lane = tid & 63, wid = tid >> 6;
    if (lane == 0) red[wid] = acc;
    __syncthreads();
    if (tid == 0) {
        const float s = red[0] + red[1] + red[2] + red[3] + b_lin[0];
        float r = fmaxf(s, 0.f) + log1pf(expf(-fabsf(s)));
        if (l >= lens[b]) r = 1.0f;
        ranges[bl] = r;
    }
}

__global__ __launch_bounds__(256) void weights_kernel(
    const float* __restrict__ ranges, const float* __restrict__ means,
    const int* __restrict__ lens, float* __restrict__ weights, int T)
{
    const int b = blockIdx.y;
    const int t = blockIdx.x * 256 + threadIdx.x;
    __shared__ float sm[NL], sinv[NL], sc[NL];
    const int len = lens[b];
    for (int l = threadIdx.x; l < NL; l += 256) {
        const float r = ranges[b * NL + l];
        const float inv = 1.f / r;
        sm[l] = means[b * NL + l];
        sinv[l] = inv;
        sc[l] = (l < len) ? 0.3989422804014327f * inv : 0.f;
    }
    __syncthreads();
    if (t >= T) return;
    const float ft = (float)t + 0.5f;
    float sum = 0.f;
    #pragma unroll 4
    for (int l = 0; l < NL; ++l) {
        const float z = (ft - sm[l]) * sinv[l];
        sum += sc[l] * __expf(-0.5f * z * z);
    }
    const float dinv = 1.f / (sum + 1e-20f);
    #pragma unroll 4
    for (int l = 0; l < NL; ++l) {
        const float z = (ft - sm[l]) * sinv[l];
        weights[((size_t)b * NL + l) * T + t] = sc[l] * __expf(-0.5f * z * z) * dinv;
    }
}

#define BM 64
#define BN 64
#define BK 16
__global__ __launch_bounds__(256) void gemm_f32_kernel(
    const float* __restrict__ xx, const float* __restrict__ weights,
    float* __restrict__ out, int T)
{
    const int b  = blockIdx.z;
    const int t0 = blockIdx.y * BM;
    const int d0 = blockIdx.x * BN;
    const float* __restrict__ W = weights + (size_t)b * NL * T;
    const float* __restrict__ X = xx + (size_t)b * NL * ND;
    float* __restrict__ O = out + (size_t)b * T * ND;
    __shared__ float As[BK][BM];
    __shared__ float Bs[BK][BN];
    const int tid = threadIdx.x;
    const int tx = tid & 15;
    const int ty = tid >> 4;
    const int lr = tid >> 4;
    const int lc = (tid & 15) * 4;
    const bool vec_ok = (t0 + BM <= T) && ((T & 3) == 0);
    float acc[4][4] = {};
    for (int l0 = 0; l0 < NL; l0 += BK) {
        if (vec_ok) {
            *(float4*)&As[lr][lc] = *(const float4*)&W[(size_t)(l0 + lr) * T + t0 + lc];
        } else {
            #pragma unroll
            for (int j = 0; j < 4; ++j) {
                const int tcol = t0 + lc + j;
                As[lr][lc + j] = (tcol < T) ? W[(size_t)(l0 + lr) * T + tcol] : 0.f;
            }
        }
        *(float4*)&Bs[lr][lc] = *(const float4*)&X[(size_t)(l0 + lr) * ND + d0 + lc];
        __syncthreads();
        #pragma unroll
        for (int k = 0; k < BK; ++k) {
            float a[4], bb[4];
            *(float4*)a  = *(const float4*)&As[k][ty * 4];
            *(float4*)bb = *(const float4*)&Bs[k][tx * 4];
            #pragma unroll
            for (int i = 0; i < 4; ++i)
                #pragma unroll
                for (int j = 0; j < 4; ++j)
                    acc[i][j] += a[i] * bb[j];
        }
        __syncthreads();
    }
    #pragma unroll
    for (int i = 0; i < 4; ++i) {
        const int t = t0 + ty * 4 + i;
        if (t < T)
            *(float4*)&O[(size_t)t * ND + d0 + tx * 4] =
                make_float4(acc[i][0], acc[i][1], acc[i][2], acc[i][3]);
    }
}

// ============================================================================
extern "C" void kernel_launch(void* const* d_in, const int* in_sizes, int n_in,
                              void* d_out, int out_size, void* d_ws, size_t ws_size,
                              hipStream_t stream) {
    const float* x     = (const float*)d_in[0];
    const float* df    = (const float*)d_in[1];
    const int*   di    = (const int*)  d_in[2];
    const float* en    = (const float*)d_in[3];
    const float* pi    = (const float*)d_in[4];
    const int*   lens  = (const int*)  d_in[5];
    const float* w_dur = (const float*)d_in[6];
    const float* b_dur = (const float*)d_in[7];
    const float* w_en  = (const float*)d_in[8];
    const float* b_en  = (const float*)d_in[9];
    const float* w_pi  = (const float*)d_in[10];
    const float* b_pi  = (const float*)d_in[11];
    const float* w_lin = (const float*)d_in[12];
    const float* b_lin = (const float*)d_in[13];

    const int B = NB, L = NL, D = ND;
    const int T = out_size / (B * (L + D));
    const int MT = (T + 63) / 64;                // # of 64-t tiles

    float* xup  = (float*)d_out;                 // (B,T,D)
    float* wout = xup + (size_t)B * T * D;       // (B,L,T)

    const size_t XbBytes = (size_t)B * L * D * 2;
    const size_t need = XbBytes + (size_t)B * L * sizeof(float);

    if (ws_size >= need) {
        unsigned short* Xb = (unsigned short*)d_ws;
        float* ranges = (float*)(Xb + (size_t)B * L * D);

        hipLaunchKernelGGL(fuse2_kernel, dim3(B * 64), dim3(256), 0, stream,
                           x, df, en, pi, lens, w_dur, b_dur, w_en, b_en,
                           w_pi, b_pi, w_lin, b_lin, Xb, ranges);
        hipLaunchKernelGGL(fusedwg2_kernel, dim3(MT * 32), dim3(512), 0, stream,
                           Xb, ranges, di, lens, wout, xup, T);
    } else {
        float* xx     = (float*)d_ws;
        float* ranges = xx + (size_t)B * L * D;
        float* means  = ranges + (size_t)B * L;
        hipLaunchKernelGGL(fuse_kernel, dim3(B * L), dim3(256), 0, stream,
                           x, df, en, pi, lens, w_dur, b_dur, w_en, b_en,
                           w_pi, b_pi, w_lin, b_lin, xx, ranges);
        hipLaunchKernelGGL(means_kernel, dim3(B), dim3(512), 0, stream, di, means);
        hipLaunchKernelGGL(weights_kernel, dim3((T + 255) / 256, B), dim3(256), 0, stream,
                           ranges, means, lens, wout, T);
        hipLaunchKernelGGL(gemm_f32_kernel, dim3(D / BN, (T + BM - 1) / BM, B), dim3(256), 0, stream,
                           xx, wout, xup, T);
    }
}